// Round 6
// baseline (481.713 us; speedup 1.0000x reference)
//
#include <hip/hip_runtime.h>

// TranslationInvariantMP — fully fused 2-pass version (MI355X/gfx950).
// Linearity: agg(x) @ W == agg(x @ W), so each pass is
//   pass0: h0 = elu( TI-agg(x)  @ W0 )          -> out[:, 0:64]
//   pass1: h1 = elu( agg(h0)    @ W1 + b1 )     -> out[:, 64:128]
// No scratch, no standalone GEMM passes.
//
// Per wave: 8 vertices. Gather phase: lane=(tq=vertex-in-quad, fq=float4 slice),
// 16-lane groups each load one 256B source row per global_load_dwordx4.
// k-loop is software-pipelined (double-buffered, 4 loads in flight x 2 groups).
// Epilogue: agg rows staged in LDS, W column held in 64 VGPRs (loaded after the
// k-loop so the allocator reuses pipeline registers), per-vertex 64x64 matvec.

constexpr int VN  = 100000;
constexpr int KN  = 32;
constexpr int FN  = 64;
constexpr int WPB = 4;               // waves per block
constexpr int TPW = 8;               // vertices per wave
constexpr int VPB = WPB * TPW;       // 32 -> 3125 blocks exact

template <bool FIRST, bool BIAS, int RBYTES>
__global__ __launch_bounds__(256, 4)   // <=128 VGPR, 16 waves/CU
void fused_mp(const float* __restrict__ src,    // gather source, rows RBYTES apart
              const int*   __restrict__ nbidx,  // [VN][32] int32
              const float* __restrict__ distsq, // [VN][32] f32
              const float* __restrict__ Wmat,   // [64][64]
              const float* __restrict__ bias,   // [64] or nullptr
              float*       __restrict__ out,    // [VN][128]
              int out_col)
{
    const int lane = threadIdx.x & 63;
    const int wid  = threadIdx.x >> 6;
    const int tq   = lane >> 4;
    const int fq   = lane & 15;

    __shared__ float s_wo[WPB][TPW * 68];    // (w, byte-offset) pairs, 68f stride
    __shared__ float s_acc[WPB][TPW * 68];   // aggregated rows for the epilogue

    const int vbase = (blockIdx.x * WPB + wid) * TPW;

    // ---- stage (w_k, byte-offset_k) for this wave's 8 vertices ----
    {
        float4 d4 = ((const float4*)(distsq + (size_t)vbase * KN))[lane];
        int4   i4 = ((const int4*)  (nbidx  + (size_t)vbase * KN))[lane];
        const int s = 4 * lane;                      // flat k-slot (v = s/32, k = s%32)
        float* dst = s_wo[wid] + (s >> 5) * 68 + (s & 31) * 2;
        float4 lo, hi;
        lo.x = __expf(-10.0f * d4.x); lo.y = __int_as_float(i4.x * RBYTES);
        lo.z = __expf(-10.0f * d4.y); lo.w = __int_as_float(i4.y * RBYTES);
        hi.x = __expf(-10.0f * d4.z); hi.y = __int_as_float(i4.z * RBYTES);
        hi.z = __expf(-10.0f * d4.w); hi.w = __int_as_float(i4.w * RBYTES);
        ((float4*)dst)[0] = lo;
        ((float4*)dst)[1] = hi;
        // same-wave DS in-order; per-wid slice -> no barrier needed
    }

    const char*  sb  = (const char*)src + (size_t)fq * 16;
    const int    v0  = vbase + tq;           // group-0 vertex
    const int    v1  = vbase + 4 + tq;       // group-1 vertex
    const float* wo0 = s_wo[wid] + tq * 68;
    const float* wo1 = s_wo[wid] + (4 + tq) * 68;

    float4 self0, self1;
    if (FIRST) {                              // issue early, consumed at the end
        self0 = *(const float4*)(sb + (size_t)v0 * RBYTES);
        self1 = *(const float4*)(sb + (size_t)v1 * RBYTES);
    }

    float4 acc0 = {0, 0, 0, 0}, acc1 = {0, 0, 0, 0};
    float  wsum0 = 0.0f, wsum1 = 0.0f;

    // ---- software-pipelined gather: 4 loads in flight per buffer set ----
    float4 p0 = ((const float4*)wo0)[0];      // {w_k, o_k, w_k1, o_k1}
    float4 p1 = ((const float4*)wo1)[0];
    float4 xa0 = *(const float4*)(sb + __float_as_int(p0.y));
    float4 xa1 = *(const float4*)(sb + __float_as_int(p0.w));
    float4 xb0 = *(const float4*)(sb + __float_as_int(p1.y));
    float4 xb1 = *(const float4*)(sb + __float_as_int(p1.w));

#pragma unroll
    for (int k = 2; k <= KN; k += 2) {
        float4 q0, q1, ya0, ya1, yb0, yb1;
        if (k < KN) {                         // compile-time (fully unrolled)
            q0  = ((const float4*)wo0)[k >> 1];
            q1  = ((const float4*)wo1)[k >> 1];
            ya0 = *(const float4*)(sb + __float_as_int(q0.y));
            ya1 = *(const float4*)(sb + __float_as_int(q0.w));
            yb0 = *(const float4*)(sb + __float_as_int(q1.y));
            yb1 = *(const float4*)(sb + __float_as_int(q1.w));
        }
        acc0.x += p0.x * xa0.x + p0.z * xa1.x;
        acc0.y += p0.x * xa0.y + p0.z * xa1.y;
        acc0.z += p0.x * xa0.z + p0.z * xa1.z;
        acc0.w += p0.x * xa0.w + p0.z * xa1.w;
        acc1.x += p1.x * xb0.x + p1.z * xb1.x;
        acc1.y += p1.x * xb0.y + p1.z * xb1.y;
        acc1.z += p1.x * xb0.z + p1.z * xb1.z;
        acc1.w += p1.x * xb0.w + p1.z * xb1.w;
        if (FIRST) { wsum0 += p0.x + p0.z; wsum1 += p1.x + p1.z; }
        if (k < KN) {
            p0 = q0; p1 = q1;
            xa0 = ya0; xa1 = ya1; xb0 = yb0; xb1 = yb1;
        }
    }

    constexpr float invK = 1.0f / KN;
    if (FIRST) {                              // translation invariance
        acc0.x -= self0.x * wsum0; acc0.y -= self0.y * wsum0;
        acc0.z -= self0.z * wsum0; acc0.w -= self0.w * wsum0;
        acc1.x -= self1.x * wsum1; acc1.y -= self1.y * wsum1;
        acc1.z -= self1.z * wsum1; acc1.w -= self1.w * wsum1;
    }
    acc0.x *= invK; acc0.y *= invK; acc0.z *= invK; acc0.w *= invK;
    acc1.x *= invK; acc1.y *= invK; acc1.z *= invK; acc1.w *= invK;

    *(float4*)(s_acc[wid] + tq * 68 + fq * 4)       = acc0;
    *(float4*)(s_acc[wid] + (4 + tq) * 68 + fq * 4) = acc1;
    // same-wave DS in-order; epilogue below reads only this wid's slice

    // ---- epilogue: h[v][j] = elu( sum_f agg[v][f] * W[f][j] (+ b[j]) ) ----
    float wc[FN];                             // lane j holds W[:,j]
#pragma unroll
    for (int f = 0; f < FN; ++f) wc[f] = Wmat[f * FN + lane];
    const float hb = BIAS ? bias[lane] : 0.0f;

#pragma unroll
    for (int v = 0; v < TPW; ++v) {
        const float4* ar = (const float4*)(s_acc[wid] + v * 68);
        float h0 = hb, h1 = 0.0f, h2 = 0.0f, h3 = 0.0f;
#pragma unroll
        for (int f4 = 0; f4 < 16; f4 += 4) {
            float4 a0 = ar[f4 + 0], a1 = ar[f4 + 1], a2 = ar[f4 + 2], a3 = ar[f4 + 3];
            h0 += a0.x * wc[4*f4 + 0]  + a0.y * wc[4*f4 + 1]
                + a0.z * wc[4*f4 + 2]  + a0.w * wc[4*f4 + 3];
            h1 += a1.x * wc[4*f4 + 4]  + a1.y * wc[4*f4 + 5]
                + a1.z * wc[4*f4 + 6]  + a1.w * wc[4*f4 + 7];
            h2 += a2.x * wc[4*f4 + 8]  + a2.y * wc[4*f4 + 9]
                + a2.z * wc[4*f4 + 10] + a2.w * wc[4*f4 + 11];
            h3 += a3.x * wc[4*f4 + 12] + a3.y * wc[4*f4 + 13]
                + a3.z * wc[4*f4 + 14] + a3.w * wc[4*f4 + 15];
        }
        float h = (h0 + h1) + (h2 + h3);
        h = (h > 0.0f) ? h : __expf(h) - 1.0f;
        out[(size_t)(vbase + v) * 128 + out_col + lane] = h;
    }
}

extern "C" void kernel_launch(void* const* d_in, const int* in_sizes, int n_in,
                              void* d_out, int out_size, void* d_ws, size_t ws_size,
                              hipStream_t stream) {
    const float* x   = (const float*)d_in[0];
    const int*   nb  = (const int*)  d_in[1];
    const float* dsq = (const float*)d_in[2];
    const float* W0  = (const float*)d_in[3];
    const float* W1  = (const float*)d_in[4];
    const float* b1  = (const float*)d_in[5];
    float* out = (float*)d_out;

    const int blocks = VN / VPB;   // 3125 exact

    // pass 0: h0 = elu( TI-agg(x) @ W0 )        -> out[:, 0:64]   (x rows 256B)
    fused_mp<true,  false, 256><<<blocks, 256, 0, stream>>>(x,   nb, dsq, W0, nullptr, out, 0);
    // pass 1: h1 = elu( agg(h0) @ W1 + b1 )     -> out[:, 64:128] (h0 rows 512B in out)
    fused_mp<false, true,  512><<<blocks, 256, 0, stream>>>(out, nb, dsq, W1, b1,      out, 64);
}